// Round 1
// baseline (531.279 us; speedup 1.0000x reference)
//
#include <hip/hip_runtime.h>
#include <hip/hip_bf16.h>

typedef __bf16 bf16x8 __attribute__((ext_vector_type(8)));
typedef __bf16 bf16x4 __attribute__((ext_vector_type(4)));
typedef float f32x4 __attribute__((ext_vector_type(4)));

#define T_SEQ 2048
#define EMB 1024
#define NH 16
#define DV 64

// ---------------- transpose + fp32->bf16 convert ----------------
// dst[b][c][r] = src[b][r][c];  grid (C/32, R/32, nbatch), block (32,8)
__global__ void transpose_cvt(const float* __restrict__ src, __bf16* __restrict__ dst,
                              int R, int C, long src_bstride, long dst_bstride) {
    __shared__ float tile[32][33];
    const int b = blockIdx.z;
    const float* s = src + (long)b * src_bstride;
    __bf16* d = dst + (long)b * dst_bstride;
    const int c0 = blockIdx.x * 32, r0 = blockIdx.y * 32;
    #pragma unroll
    for (int i = threadIdx.y; i < 32; i += 8)
        tile[i][threadIdx.x] = s[(long)(r0 + i) * C + c0 + threadIdx.x];
    __syncthreads();
    #pragma unroll
    for (int i = threadIdx.y; i < 32; i += 8)
        d[(long)(c0 + i) * R + r0 + threadIdx.x] = (__bf16)tile[threadIdx.x][i];
}

// ---------------- LayerNorm: fp32 in -> bf16 out ----------------
// one block (256 thr) per row of 1024
__global__ void ln_kernel(const float* __restrict__ x, const float* __restrict__ g,
                          const float* __restrict__ be, __bf16* __restrict__ out) {
    const int row = blockIdx.x;
    const float4 xv = reinterpret_cast<const float4*>(x + (long)row * EMB)[threadIdx.x];
    float s = xv.x + xv.y + xv.z + xv.w;
    float sq = xv.x * xv.x + xv.y * xv.y + xv.z * xv.z + xv.w * xv.w;
    #pragma unroll
    for (int off = 32; off; off >>= 1) { s += __shfl_down(s, off); sq += __shfl_down(sq, off); }
    __shared__ float red[8];
    const int w = threadIdx.x >> 6, lane = threadIdx.x & 63;
    if (lane == 0) { red[w] = s; red[4 + w] = sq; }
    __syncthreads();
    if (threadIdx.x == 0) {
        float st = red[0] + red[1] + red[2] + red[3];
        float sqt = red[4] + red[5] + red[6] + red[7];
        float mean = st * (1.0f / EMB);
        float var = sqt * (1.0f / EMB) - mean * mean;
        red[0] = mean; red[1] = rsqrtf(var + 1e-5f);
    }
    __syncthreads();
    const float mean = red[0], rstd = red[1];
    const float4 gv = reinterpret_cast<const float4*>(g)[threadIdx.x];
    const float4 bv = reinterpret_cast<const float4*>(be)[threadIdx.x];
    bf16x4 o;
    o[0] = (__bf16)((xv.x - mean) * rstd * gv.x + bv.x);
    o[1] = (__bf16)((xv.y - mean) * rstd * gv.y + bv.y);
    o[2] = (__bf16)((xv.z - mean) * rstd * gv.z + bv.z);
    o[3] = (__bf16)((xv.w - mean) * rstd * gv.w + bv.w);
    *reinterpret_cast<bf16x4*>(out + (long)row * EMB + threadIdx.x * 4) = o;
}

// ---------------- bf16 GEMM (NT): C[M][N] = A[M][K] * BT[N][K]^T ----------------
// 128x128 tile, BK=64, 4 waves 2x2, 4x4 16x16x32 fragments per wave.
template <int OUT_BF16, int RELU, int HAS_BIAS, int HAS_RES>
__global__ __launch_bounds__(256)
void gemm_nt(const __bf16* __restrict__ A, const __bf16* __restrict__ BT,
             const float* __restrict__ bias, const float* __restrict__ res,
             void* __restrict__ outp, int M, int N, int K) {
    __shared__ __bf16 As[128][72];   // +8 pad: 144B row stride -> 2-way bank alias (free)
    __shared__ __bf16 Bs[128][72];
    const int t = threadIdx.x;
    const int w = t >> 6, lane = t & 63;
    const int wm = (w >> 1) * 64, wn = (w & 1) * 64;
    const int m0 = blockIdx.y * 128, n0 = blockIdx.x * 128;
    const int rA = lane & 15, kA = (lane >> 4) * 8;
    const int srow = t >> 3, sseg = t & 7;

    f32x4 acc[4][4] = {};
    for (int k0 = 0; k0 < K; k0 += 64) {
        bf16x8 ar[4], br[4];
        #pragma unroll
        for (int i = 0; i < 4; i++) {
            const int row = srow + 32 * i;
            ar[i] = *reinterpret_cast<const bf16x8*>(A + (long)(m0 + row) * K + k0 + sseg * 8);
            br[i] = *reinterpret_cast<const bf16x8*>(BT + (long)(n0 + row) * K + k0 + sseg * 8);
        }
        __syncthreads();
        #pragma unroll
        for (int i = 0; i < 4; i++) {
            const int row = srow + 32 * i;
            *reinterpret_cast<bf16x8*>(&As[row][sseg * 8]) = ar[i];
            *reinterpret_cast<bf16x8*>(&Bs[row][sseg * 8]) = br[i];
        }
        __syncthreads();
        #pragma unroll
        for (int kk = 0; kk < 2; kk++) {
            bf16x8 af[4], bfr[4];
            #pragma unroll
            for (int m = 0; m < 4; m++)
                af[m] = *reinterpret_cast<const bf16x8*>(&As[wm + m * 16 + rA][kk * 32 + kA]);
            #pragma unroll
            for (int n = 0; n < 4; n++)
                bfr[n] = *reinterpret_cast<const bf16x8*>(&Bs[wn + n * 16 + rA][kk * 32 + kA]);
            #pragma unroll
            for (int m = 0; m < 4; m++)
                #pragma unroll
                for (int n = 0; n < 4; n++)
                    acc[m][n] = __builtin_amdgcn_mfma_f32_16x16x32_bf16(af[m], bfr[n], acc[m][n], 0, 0, 0);
        }
    }
    // epilogue: C/D layout col=lane&15, row=(lane>>4)*4+reg
    const int rl = (lane >> 4) * 4, cl = lane & 15;
    #pragma unroll
    for (int m = 0; m < 4; m++) {
        #pragma unroll
        for (int n = 0; n < 4; n++) {
            const int gc = n0 + wn + n * 16 + cl;
            float bval = 0.0f;
            if (HAS_BIAS) bval = bias[gc];
            #pragma unroll
            for (int r = 0; r < 4; r++) {
                const int gr = m0 + wm + m * 16 + rl + r;
                float v = acc[m][n][r] + bval;
                if (HAS_RES) v += res[(long)gr * N + gc];
                if (RELU) v = fmaxf(v, 0.0f);
                if (OUT_BF16) ((__bf16*)outp)[(long)gr * N + gc] = (__bf16)v;
                else          ((float*)outp)[(long)gr * N + gc] = v;
            }
        }
    }
}

// ---------------- causal flash attention ----------------
// qkv: [B*T][3072] bf16 (cols 0..1023 Q, 1024..2047 K, 2048..3071 V, per head h: h*64+d)
// out: attn [B*T][1024] bf16. grid (T/128, B*H), 256 thr (4 waves x 32 Q-rows).
__global__ __launch_bounds__(256)
void attn_kernel(const __bf16* __restrict__ qkv, __bf16* __restrict__ attn) {
    const int bh = blockIdx.y, b = bh >> 4, h = bh & 15;
    const int w = threadIdx.x >> 6, lane = threadIdx.x & 63;
    const int q0 = blockIdx.x * 128, qw = q0 + w * 32;
    const int rA = lane & 15, kA = (lane >> 4) * 8, rl = (lane >> 4) * 4;
    const long RS = 3072;
    const __bf16* qb = qkv + (long)b * T_SEQ * RS + h * 64;
    const __bf16* kb = qb + 1024;
    const __bf16* vb = qb + 2048;

    __shared__ __bf16 Vs[64][40];       // V^T tile, shared by all waves
    __shared__ __bf16 Ps[4][32][40];    // per-wave P redistribution buffer

    bf16x8 qf[2][2];
    #pragma unroll
    for (int rt = 0; rt < 2; rt++)
        #pragma unroll
        for (int kc = 0; kc < 2; kc++)
            qf[rt][kc] = *reinterpret_cast<const bf16x8*>(qb + (long)(qw + rt * 16 + rA) * RS + kc * 32 + kA);

    f32x4 o[2][4] = {};
    float mr[2][4], lr[2][4];
    #pragma unroll
    for (int rt = 0; rt < 2; rt++)
        #pragma unroll
        for (int r = 0; r < 4; r++) { mr[rt][r] = -INFINITY; lr[rt][r] = 0.0f; }

    const int sv = threadIdx.x >> 3, dsg = threadIdx.x & 7;
    const int kv_end = q0 + 128;
    for (int kv0 = 0; kv0 < kv_end; kv0 += 32) {
        // stage V^T cooperatively (row stride 40 elems = 80B: 16B-aligned, 2-way bank alias)
        bf16x8 vv = *reinterpret_cast<const bf16x8*>(vb + (long)(kv0 + sv) * RS + dsg * 8);
        __syncthreads();   // prior iteration's Vs reads done
        #pragma unroll
        for (int i = 0; i < 8; i++) Vs[dsg * 8 + i][sv] = vv[i];
        __syncthreads();

        // S = Q K^T  (K fragments direct from global; L2-resident)
        bf16x8 kf[2][2];
        #pragma unroll
        for (int c = 0; c < 2; c++)
            #pragma unroll
            for (int kc = 0; kc < 2; kc++)
                kf[c][kc] = *reinterpret_cast<const bf16x8*>(kb + (long)(kv0 + c * 16 + rA) * RS + kc * 32 + kA);
        f32x4 sa[2][2] = {};
        #pragma unroll
        for (int rt = 0; rt < 2; rt++)
            #pragma unroll
            for (int c = 0; c < 2; c++)
                #pragma unroll
                for (int kc = 0; kc < 2; kc++)
                    sa[rt][c] = __builtin_amdgcn_mfma_f32_16x16x32_bf16(qf[rt][kc], kf[c][kc], sa[rt][c], 0, 0, 0);

        // online softmax (fp32), P -> bf16 via per-wave LDS
        #pragma unroll
        for (int rt = 0; rt < 2; rt++) {
            #pragma unroll
            for (int r = 0; r < 4; r++) {
                const int gr = qw + rt * 16 + rl + r;
                float s0 = sa[rt][0][r] * 0.03125f;   // * C^-0.5 = 1/32
                float s1 = sa[rt][1][r] * 0.03125f;
                if (kv0 + (lane & 15) > gr)      s0 = -INFINITY;
                if (kv0 + 16 + (lane & 15) > gr) s1 = -INFINITY;
                float tm = fmaxf(s0, s1);
                #pragma unroll
                for (int msk = 1; msk < 16; msk <<= 1) tm = fmaxf(tm, __shfl_xor(tm, msk));
                const float mn = fmaxf(mr[rt][r], tm);
                const float sc = __expf(mr[rt][r] - mn);
                const float p0 = __expf(s0 - mn);
                const float p1 = __expf(s1 - mn);
                float rs = p0 + p1;
                #pragma unroll
                for (int msk = 1; msk < 16; msk <<= 1) rs += __shfl_xor(rs, msk);
                lr[rt][r] = lr[rt][r] * sc + rs;
                mr[rt][r] = mn;
                #pragma unroll
                for (int n = 0; n < 4; n++) o[rt][n][r] *= sc;
                Ps[w][rt * 16 + rl + r][lane & 15]        = (__bf16)p0;
                Ps[w][rt * 16 + rl + r][16 + (lane & 15)] = (__bf16)p1;
            }
        }
        // cross-lane LDS within the same wave: drain DS queue (no barrier needed)
        asm volatile("s_waitcnt lgkmcnt(0)" ::: "memory");

        // O += P V
        bf16x8 bv[4];
        #pragma unroll
        for (int n = 0; n < 4; n++)
            bv[n] = *reinterpret_cast<const bf16x8*>(&Vs[n * 16 + rA][kA]);
        #pragma unroll
        for (int rt = 0; rt < 2; rt++) {
            bf16x8 ap = *reinterpret_cast<const bf16x8*>(&Ps[w][rt * 16 + rA][kA]);
            #pragma unroll
            for (int n = 0; n < 4; n++)
                o[rt][n] = __builtin_amdgcn_mfma_f32_16x16x32_bf16(ap, bv[n], o[rt][n], 0, 0, 0);
        }
    }

    #pragma unroll
    for (int rt = 0; rt < 2; rt++)
        #pragma unroll
        for (int n = 0; n < 4; n++)
            #pragma unroll
            for (int r = 0; r < 4; r++) {
                const int gr = qw + rt * 16 + rl + r;
                attn[(long)(b * T_SEQ + gr) * EMB + h * 64 + n * 16 + (lane & 15)] =
                    (__bf16)(o[rt][n][r] / lr[rt][r]);
            }
}

// ---------------- launch ----------------
extern "C" void kernel_launch(void* const* d_in, const int* in_sizes, int n_in,
                              void* d_out, int out_size, void* d_ws, size_t ws_size,
                              hipStream_t stream) {
    const float* x      = (const float*)d_in[0];
    const float* wq     = (const float*)d_in[1];
    const float* wk     = (const float*)d_in[2];
    const float* wv     = (const float*)d_in[3];
    const float* w_proj = (const float*)d_in[4];
    const float* b_proj = (const float*)d_in[5];
    const float* w1     = (const float*)d_in[6];
    const float* b1     = (const float*)d_in[7];
    const float* w2     = (const float*)d_in[8];
    const float* b2     = (const float*)d_in[9];
    const float* g1     = (const float*)d_in[10];
    const float* be1    = (const float*)d_in[11];
    const float* g2     = (const float*)d_in[12];
    const float* be2    = (const float*)d_in[13];
    float* out = (float*)d_out;

    char* ws = (char*)d_ws;
    __bf16* WqkvT = (__bf16*)ws;  ws += 3072L * 1024 * 2;   // [3072][1024]
    __bf16* WprojT = (__bf16*)ws; ws += 1024L * 1024 * 2;   // [1024][1024]
    __bf16* W1T = (__bf16*)ws;    ws += 4096L * 1024 * 2;   // [4096][1024]
    __bf16* W2T = (__bf16*)ws;    ws += 1024L * 4096 * 2;   // [1024][4096]
    __bf16* h1  = (__bf16*)ws;    ws += 4096L * 1024 * 2;   // LN1 out; reused as LN2 out
    __bf16* qkvb = (__bf16*)ws;                              // [4096][3072]
    __bf16* attnb = (__bf16*)(ws + 4096L * 3072 * 2);        // [4096][1024]
    __bf16* ffb = (__bf16*)ws;    ws += 4096L * 3072 * 2 + 4096L * 1024 * 2; // ff overlays qkv+attn
    float* x2 = (float*)ws;                                  // [4096][1024] fp32

    const dim3 tb(32, 8);
    transpose_cvt<<<dim3(2, 32, 16), tb, 0, stream>>>(wq, WqkvT,               1024, 64, 65536L, 65536L);
    transpose_cvt<<<dim3(2, 32, 16), tb, 0, stream>>>(wk, WqkvT + 1024L * 1024, 1024, 64, 65536L, 65536L);
    transpose_cvt<<<dim3(2, 32, 16), tb, 0, stream>>>(wv, WqkvT + 2048L * 1024, 1024, 64, 65536L, 65536L);
    transpose_cvt<<<dim3(32, 32, 1),  tb, 0, stream>>>(w_proj, WprojT, 1024, 1024, 0, 0);
    transpose_cvt<<<dim3(128, 32, 1), tb, 0, stream>>>(w1, W1T, 1024, 4096, 0, 0);
    transpose_cvt<<<dim3(32, 128, 1), tb, 0, stream>>>(w2, W2T, 4096, 1024, 0, 0);

    ln_kernel<<<4096, 256, 0, stream>>>(x, g1, be1, h1);
    gemm_nt<1, 0, 0, 0><<<dim3(24, 32), 256, 0, stream>>>(h1, WqkvT, nullptr, nullptr, qkvb, 4096, 3072, 1024);
    attn_kernel<<<dim3(16, 32), 256, 0, stream>>>(qkvb, attnb);
    gemm_nt<0, 0, 1, 1><<<dim3(8, 32), 256, 0, stream>>>(attnb, WprojT, b_proj, x, x2, 4096, 1024, 1024);
    ln_kernel<<<4096, 256, 0, stream>>>(x2, g2, be2, h1);
    gemm_nt<1, 1, 1, 0><<<dim3(32, 32), 256, 0, stream>>>(h1, W1T, b1, nullptr, ffb, 4096, 4096, 1024);
    gemm_nt<0, 0, 1, 1><<<dim3(8, 32), 256, 0, stream>>>(ffb, W2T, b2, x2, out, 4096, 1024, 4096);
}

// Round 2
// 489.689 us; speedup vs baseline: 1.0849x; 1.0849x over previous
//
#include <hip/hip_runtime.h>
#include <hip/hip_bf16.h>

typedef __bf16 bf16x8 __attribute__((ext_vector_type(8)));
typedef __bf16 bf16x4 __attribute__((ext_vector_type(4)));
typedef float f32x4 __attribute__((ext_vector_type(4)));

#define T_SEQ 2048
#define EMB 1024
#define NH 16
#define DV 64

// ---------------- transpose + fp32->bf16 convert (with scale) ----------------
// dst[b][c][r] = src[b][r][c] * scale;  grid (C/32, R/32, nbatch), block (32,8)
__global__ void transpose_cvt(const float* __restrict__ src, __bf16* __restrict__ dst,
                              int R, int C, long src_bstride, long dst_bstride, float scale) {
    __shared__ float tile[32][33];
    const int b = blockIdx.z;
    const float* s = src + (long)b * src_bstride;
    __bf16* d = dst + (long)b * dst_bstride;
    const int c0 = blockIdx.x * 32, r0 = blockIdx.y * 32;
    #pragma unroll
    for (int i = threadIdx.y; i < 32; i += 8)
        tile[i][threadIdx.x] = s[(long)(r0 + i) * C + c0 + threadIdx.x];
    __syncthreads();
    #pragma unroll
    for (int i = threadIdx.y; i < 32; i += 8)
        d[(long)(c0 + i) * R + r0 + threadIdx.x] = (__bf16)(tile[threadIdx.x][i] * scale);
}

// ---------------- V transpose: qkv -> Vt[bh][64][2048] ----------------
// grid (T/64, B*H), block 256
__global__ void vt_transpose(const __bf16* __restrict__ qkv, __bf16* __restrict__ Vt) {
    __shared__ __bf16 tile[64][72];
    const int bh = blockIdx.y, b = bh >> 4, h = bh & 15;
    const int t0 = blockIdx.x * 64;
    const __bf16* src = qkv + (long)b * T_SEQ * 3072 + 2048 + h * 64;
    const int tt = threadIdx.x >> 3, seg = threadIdx.x & 7;
    #pragma unroll
    for (int half = 0; half < 2; half++) {
        const int t = half * 32 + tt;
        bf16x8 v = *reinterpret_cast<const bf16x8*>(src + (long)(t0 + t) * 3072 + seg * 8);
        *reinterpret_cast<bf16x8*>(&tile[t][seg * 8]) = v;
    }
    __syncthreads();
    __bf16* dst = Vt + (long)bh * 64 * T_SEQ + t0;
    #pragma unroll
    for (int half = 0; half < 2; half++) {
        const int d = half * 32 + tt;
        bf16x8 v;
        #pragma unroll
        for (int i = 0; i < 8; i++) v[i] = tile[seg * 8 + i][d];
        *reinterpret_cast<bf16x8*>(dst + (long)d * T_SEQ + seg * 8) = v;
    }
}

// ---------------- LayerNorm: fp32 in -> bf16 out ----------------
__global__ void ln_kernel(const float* __restrict__ x, const float* __restrict__ g,
                          const float* __restrict__ be, __bf16* __restrict__ out) {
    const int row = blockIdx.x;
    const float4 xv = reinterpret_cast<const float4*>(x + (long)row * EMB)[threadIdx.x];
    float s = xv.x + xv.y + xv.z + xv.w;
    float sq = xv.x * xv.x + xv.y * xv.y + xv.z * xv.z + xv.w * xv.w;
    #pragma unroll
    for (int off = 32; off; off >>= 1) { s += __shfl_down(s, off); sq += __shfl_down(sq, off); }
    __shared__ float red[8];
    const int w = threadIdx.x >> 6, lane = threadIdx.x & 63;
    if (lane == 0) { red[w] = s; red[4 + w] = sq; }
    __syncthreads();
    if (threadIdx.x == 0) {
        float st = red[0] + red[1] + red[2] + red[3];
        float sqt = red[4] + red[5] + red[6] + red[7];
        float mean = st * (1.0f / EMB);
        float var = sqt * (1.0f / EMB) - mean * mean;
        red[0] = mean; red[1] = rsqrtf(var + 1e-5f);
    }
    __syncthreads();
    const float mean = red[0], rstd = red[1];
    const float4 gv = reinterpret_cast<const float4*>(g)[threadIdx.x];
    const float4 bv = reinterpret_cast<const float4*>(be)[threadIdx.x];
    bf16x4 o;
    o[0] = (__bf16)((xv.x - mean) * rstd * gv.x + bv.x);
    o[1] = (__bf16)((xv.y - mean) * rstd * gv.y + bv.y);
    o[2] = (__bf16)((xv.z - mean) * rstd * gv.z + bv.z);
    o[3] = (__bf16)((xv.w - mean) * rstd * gv.w + bv.w);
    *reinterpret_cast<bf16x4*>(out + (long)row * EMB + threadIdx.x * 4) = o;
}

// ---------------- bf16 GEMM (NT): C[M][N] = A[M][K] * BT[N][K]^T ----------------
template <int OUT_BF16, int RELU, int HAS_BIAS, int HAS_RES>
__global__ __launch_bounds__(256)
void gemm_nt(const __bf16* __restrict__ A, const __bf16* __restrict__ BT,
             const float* __restrict__ bias, const float* __restrict__ res,
             void* __restrict__ outp, int M, int N, int K) {
    __shared__ __bf16 As[128][72];
    __shared__ __bf16 Bs[128][72];
    const int t = threadIdx.x;
    const int w = t >> 6, lane = t & 63;
    const int wm = (w >> 1) * 64, wn = (w & 1) * 64;
    const int m0 = blockIdx.y * 128, n0 = blockIdx.x * 128;
    const int rA = lane & 15, kA = (lane >> 4) * 8;
    const int srow = t >> 3, sseg = t & 7;

    f32x4 acc[4][4] = {};
    for (int k0 = 0; k0 < K; k0 += 64) {
        bf16x8 ar[4], br[4];
        #pragma unroll
        for (int i = 0; i < 4; i++) {
            const int row = srow + 32 * i;
            ar[i] = *reinterpret_cast<const bf16x8*>(A + (long)(m0 + row) * K + k0 + sseg * 8);
            br[i] = *reinterpret_cast<const bf16x8*>(BT + (long)(n0 + row) * K + k0 + sseg * 8);
        }
        __syncthreads();
        #pragma unroll
        for (int i = 0; i < 4; i++) {
            const int row = srow + 32 * i;
            *reinterpret_cast<bf16x8*>(&As[row][sseg * 8]) = ar[i];
            *reinterpret_cast<bf16x8*>(&Bs[row][sseg * 8]) = br[i];
        }
        __syncthreads();
        #pragma unroll
        for (int kk = 0; kk < 2; kk++) {
            bf16x8 af[4], bfr[4];
            #pragma unroll
            for (int m = 0; m < 4; m++)
                af[m] = *reinterpret_cast<const bf16x8*>(&As[wm + m * 16 + rA][kk * 32 + kA]);
            #pragma unroll
            for (int n = 0; n < 4; n++)
                bfr[n] = *reinterpret_cast<const bf16x8*>(&Bs[wn + n * 16 + rA][kk * 32 + kA]);
            #pragma unroll
            for (int m = 0; m < 4; m++)
                #pragma unroll
                for (int n = 0; n < 4; n++)
                    acc[m][n] = __builtin_amdgcn_mfma_f32_16x16x32_bf16(af[m], bfr[n], acc[m][n], 0, 0, 0);
        }
    }
    const int rl = (lane >> 4) * 4, cl = lane & 15;
    #pragma unroll
    for (int m = 0; m < 4; m++) {
        #pragma unroll
        for (int n = 0; n < 4; n++) {
            const int gc = n0 + wn + n * 16 + cl;
            float bval = 0.0f;
            if (HAS_BIAS) bval = bias[gc];
            #pragma unroll
            for (int r = 0; r < 4; r++) {
                const int gr = m0 + wm + m * 16 + rl + r;
                float v = acc[m][n][r] + bval;
                if (HAS_RES) v += res[(long)gr * N + gc];
                if (RELU) v = fmaxf(v, 0.0f);
                if (OUT_BF16) ((__bf16*)outp)[(long)gr * N + gc] = (__bf16)v;
                else          ((float*)outp)[(long)gr * N + gc] = v;
            }
        }
    }
}

// ---------------- causal flash attention (barrier-free) ----------------
template <bool DIAG>
__device__ __forceinline__ void attn_step(
    const __bf16* __restrict__ kb, const __bf16* __restrict__ vt,
    __bf16 (*__restrict__ PsW)[40],
    const bf16x8 (&qf)[2][2], const bf16x8& ones,
    f32x4 (&o)[2][4], f32x4 (&l5)[2], float (&mr)[2][4],
    int kv0, int rA, int kA8, int rl, int qw)
{
    bf16x8 kf[2][2];
    #pragma unroll
    for (int c = 0; c < 2; c++)
        #pragma unroll
        for (int kc = 0; kc < 2; kc++)
            kf[c][kc] = *reinterpret_cast<const bf16x8*>(kb + (long)(kv0 + c * 16 + rA) * 3072 + kc * 32 + kA8);
    f32x4 sa[2][2] = {};
    #pragma unroll
    for (int rt = 0; rt < 2; rt++)
        #pragma unroll
        for (int c = 0; c < 2; c++)
            #pragma unroll
            for (int kc = 0; kc < 2; kc++)
                sa[rt][c] = __builtin_amdgcn_mfma_f32_16x16x32_bf16(qf[rt][kc], kf[c][kc], sa[rt][c], 0, 0, 0);

    #pragma unroll
    for (int rt = 0; rt < 2; rt++) {
        #pragma unroll
        for (int r = 0; r < 4; r++) {
            float s0 = sa[rt][0][r], s1 = sa[rt][1][r];
            if (DIAG) {
                const int gr = qw + rt * 16 + rl + r;
                if (kv0 + rA > gr)      s0 = -__builtin_inff();
                if (kv0 + 16 + rA > gr) s1 = -__builtin_inff();
            }
            float tm = fmaxf(s0, s1);
            #pragma unroll
            for (int msk = 1; msk < 16; msk <<= 1) tm = fmaxf(tm, __shfl_xor(tm, msk));
            const float mo = mr[rt][r];
            const float mn = fmaxf(mo, tm);
            mr[rt][r] = mn;
            const float sc = __expf(mo - mn);
            const float p0 = __expf(s0 - mn);
            const float p1 = __expf(s1 - mn);
            #pragma unroll
            for (int n = 0; n < 4; n++) o[rt][n][r] *= sc;
            l5[rt][r] *= sc;
            PsW[rt * 16 + rl + r][rA]      = (__bf16)p0;
            PsW[rt * 16 + rl + r][16 + rA] = (__bf16)p1;
        }
    }
    // same-wave LDS write->read: drain DS queue (in-order per wave; belt & suspenders)
    asm volatile("s_waitcnt lgkmcnt(0)" ::: "memory");

    bf16x8 bv[4];
    #pragma unroll
    for (int n = 0; n < 4; n++)
        bv[n] = *reinterpret_cast<const bf16x8*>(vt + (long)(n * 16 + rA) * T_SEQ + kv0 + kA8);
    #pragma unroll
    for (int rt = 0; rt < 2; rt++) {
        bf16x8 ap = *reinterpret_cast<const bf16x8*>(&PsW[rt * 16 + rA][kA8]);
        l5[rt] = __builtin_amdgcn_mfma_f32_16x16x32_bf16(ap, ones, l5[rt], 0, 0, 0);
        #pragma unroll
        for (int n = 0; n < 4; n++)
            o[rt][n] = __builtin_amdgcn_mfma_f32_16x16x32_bf16(ap, bv[n], o[rt][n], 0, 0, 0);
    }
}

// qkv: [B*T][3072] bf16 (Q pre-scaled by 1/32); Vt: [B*H][64][2048] bf16
// grid (T/128, B*H), 256 thr (4 waves x 32 Q-rows). No __syncthreads in loop.
__global__ __launch_bounds__(256)
void attn_kernel(const __bf16* __restrict__ qkv, const __bf16* __restrict__ Vt,
                 __bf16* __restrict__ attn) {
    const int bh = blockIdx.y, b = bh >> 4, h = bh & 15;
    const int w = threadIdx.x >> 6, lane = threadIdx.x & 63;
    const int q0 = blockIdx.x * 128, qw = q0 + w * 32;
    const int rA = lane & 15, kA8 = (lane >> 4) * 8, rl = (lane >> 4) * 4;
    const long RS = 3072;
    const __bf16* qb = qkv + (long)b * T_SEQ * RS + h * 64;
    const __bf16* kb = qb + 1024;
    const __bf16* vt = Vt + (long)bh * 64 * T_SEQ;

    __shared__ __bf16 Ps[4][32][40];
    __bf16 (*PsW)[40] = Ps[w];

    bf16x8 qf[2][2];
    #pragma unroll
    for (int rt = 0; rt < 2; rt++)
        #pragma unroll
        for (int kc = 0; kc < 2; kc++)
            qf[rt][kc] = *reinterpret_cast<const bf16x8*>(qb + (long)(qw + rt * 16 + rA) * RS + kc * 32 + kA8);

    bf16x8 ones;
    #pragma unroll
    for (int i = 0; i < 8; i++) ones[i] = (__bf16)1.0f;

    f32x4 o[2][4] = {};
    f32x4 l5[2] = {};
    float mr[2][4];
    #pragma unroll
    for (int rt = 0; rt < 2; rt++)
        #pragma unroll
        for (int r = 0; r < 4; r++) mr[rt][r] = -__builtin_inff();

    for (int kv0 = 0; kv0 < qw; kv0 += 32)
        attn_step<false>(kb, vt, PsW, qf, ones, o, l5, mr, kv0, rA, kA8, rl, qw);
    attn_step<true>(kb, vt, PsW, qf, ones, o, l5, mr, qw, rA, kA8, rl, qw);

    #pragma unroll
    for (int rt = 0; rt < 2; rt++)
        #pragma unroll
        for (int n = 0; n < 4; n++)
            #pragma unroll
            for (int r = 0; r < 4; r++) {
                const int gr = qw + rt * 16 + rl + r;
                attn[(long)(b * T_SEQ + gr) * EMB + h * 64 + n * 16 + rA] =
                    (__bf16)(o[rt][n][r] / l5[rt][r]);
            }
}

// ---------------- launch ----------------
extern "C" void kernel_launch(void* const* d_in, const int* in_sizes, int n_in,
                              void* d_out, int out_size, void* d_ws, size_t ws_size,
                              hipStream_t stream) {
    const float* x      = (const float*)d_in[0];
    const float* wq     = (const float*)d_in[1];
    const float* wk     = (const float*)d_in[2];
    const float* wv     = (const float*)d_in[3];
    const float* w_proj = (const float*)d_in[4];
    const float* b_proj = (const float*)d_in[5];
    const float* w1     = (const float*)d_in[6];
    const float* b1     = (const float*)d_in[7];
    const float* w2     = (const float*)d_in[8];
    const float* b2     = (const float*)d_in[9];
    const float* g1     = (const float*)d_in[10];
    const float* be1    = (const float*)d_in[11];
    const float* g2     = (const float*)d_in[12];
    const float* be2    = (const float*)d_in[13];
    float* out = (float*)d_out;

    char* ws = (char*)d_ws;
    __bf16* WqkvT = (__bf16*)ws;  ws += 3072L * 1024 * 2;   // [3072][1024]
    __bf16* WprojT = (__bf16*)ws; ws += 1024L * 1024 * 2;   // [1024][1024]
    __bf16* W1T = (__bf16*)ws;    ws += 4096L * 1024 * 2;   // [4096][1024]
    __bf16* W2T = (__bf16*)ws;    ws += 1024L * 4096 * 2;   // [1024][4096]
    __bf16* h1  = (__bf16*)ws;    ws += 4096L * 1024 * 2;   // LN out (reused)
    __bf16* qkvb = (__bf16*)ws;                              // [4096][3072]
    __bf16* attnb = (__bf16*)(ws + 4096L * 3072 * 2);        // [4096][1024]
    __bf16* ffb = (__bf16*)ws;    ws += 4096L * 3072 * 2 + 4096L * 1024 * 2; // overlays qkv+attn
    float* x2 = (float*)ws;                                  // [4096][1024] fp32
    __bf16* Vt = (__bf16*)ws;                                // [32][64][2048] bf16, overlays x2
                                                             // (Vt dead before proj-GEMM writes x2)

    const dim3 tb(32, 8);
    transpose_cvt<<<dim3(2, 32, 16), tb, 0, stream>>>(wq, WqkvT,                1024, 64, 65536L, 65536L, 0.03125f);
    transpose_cvt<<<dim3(2, 32, 16), tb, 0, stream>>>(wk, WqkvT + 1024L * 1024, 1024, 64, 65536L, 65536L, 1.0f);
    transpose_cvt<<<dim3(2, 32, 16), tb, 0, stream>>>(wv, WqkvT + 2048L * 1024, 1024, 64, 65536L, 65536L, 1.0f);
    transpose_cvt<<<dim3(32, 32, 1),  tb, 0, stream>>>(w_proj, WprojT, 1024, 1024, 0, 0, 1.0f);
    transpose_cvt<<<dim3(128, 32, 1), tb, 0, stream>>>(w1, W1T, 1024, 4096, 0, 0, 1.0f);
    transpose_cvt<<<dim3(32, 128, 1), tb, 0, stream>>>(w2, W2T, 4096, 1024, 0, 0, 1.0f);

    ln_kernel<<<4096, 256, 0, stream>>>(x, g1, be1, h1);
    gemm_nt<1, 0, 0, 0><<<dim3(24, 32), 256, 0, stream>>>(h1, WqkvT, nullptr, nullptr, qkvb, 4096, 3072, 1024);
    vt_transpose<<<dim3(32, 32), 256, 0, stream>>>(qkvb, Vt);
    attn_kernel<<<dim3(16, 32), 256, 0, stream>>>(qkvb, Vt, attnb);
    gemm_nt<0, 0, 1, 1><<<dim3(8, 32), 256, 0, stream>>>(attnb, WprojT, b_proj, x, x2, 4096, 1024, 1024);
    ln_kernel<<<4096, 256, 0, stream>>>(x2, g2, be2, h1);
    gemm_nt<1, 1, 1, 0><<<dim3(32, 32), 256, 0, stream>>>(h1, W1T, b1, nullptr, ffb, 4096, 4096, 1024);
    gemm_nt<0, 0, 1, 1><<<dim3(8, 32), 256, 0, stream>>>(ffb, W2T, b2, x2, out, 4096, 1024, 4096);
}

// Round 3
// 422.330 us; speedup vs baseline: 1.2580x; 1.1595x over previous
//
#include <hip/hip_runtime.h>
#include <hip/hip_bf16.h>

typedef __bf16 bf16x8 __attribute__((ext_vector_type(8)));
typedef __bf16 bf16x4 __attribute__((ext_vector_type(4)));
typedef float f32x4 __attribute__((ext_vector_type(4)));

#define T_SEQ 2048
#define EMB 1024
#define NH 16
#define DV 64

// ---------------- transpose + fp32->bf16 convert (with scale) ----------------
__global__ void transpose_cvt(const float* __restrict__ src, __bf16* __restrict__ dst,
                              int R, int C, long src_bstride, long dst_bstride, float scale) {
    __shared__ float tile[32][33];
    const int b = blockIdx.z;
    const float* s = src + (long)b * src_bstride;
    __bf16* d = dst + (long)b * dst_bstride;
    const int c0 = blockIdx.x * 32, r0 = blockIdx.y * 32;
    #pragma unroll
    for (int i = threadIdx.y; i < 32; i += 8)
        tile[i][threadIdx.x] = s[(long)(r0 + i) * C + c0 + threadIdx.x];
    __syncthreads();
    #pragma unroll
    for (int i = threadIdx.y; i < 32; i += 8)
        d[(long)(c0 + i) * R + r0 + threadIdx.x] = (__bf16)(tile[threadIdx.x][i] * scale);
}

// ---------------- V transpose: qkv -> Vt[bh][64][2048] ----------------
__global__ void vt_transpose(const __bf16* __restrict__ qkv, __bf16* __restrict__ Vt) {
    __shared__ __bf16 tile[64][72];
    const int bh = blockIdx.y, b = bh >> 4, h = bh & 15;
    const int t0 = blockIdx.x * 64;
    const __bf16* src = qkv + (long)b * T_SEQ * 3072 + 2048 + h * 64;
    const int tt = threadIdx.x >> 3, seg = threadIdx.x & 7;
    #pragma unroll
    for (int half = 0; half < 2; half++) {
        const int t = half * 32 + tt;
        bf16x8 v = *reinterpret_cast<const bf16x8*>(src + (long)(t0 + t) * 3072 + seg * 8);
        *reinterpret_cast<bf16x8*>(&tile[t][seg * 8]) = v;
    }
    __syncthreads();
    __bf16* dst = Vt + (long)bh * 64 * T_SEQ + t0;
    #pragma unroll
    for (int half = 0; half < 2; half++) {
        const int d = half * 32 + tt;
        bf16x8 v;
        #pragma unroll
        for (int i = 0; i < 8; i++) v[i] = tile[seg * 8 + i][d];
        *reinterpret_cast<bf16x8*>(dst + (long)d * T_SEQ + seg * 8) = v;
    }
}

// ---------------- LayerNorm: fp32 in -> bf16 out ----------------
__global__ void ln_kernel(const float* __restrict__ x, const float* __restrict__ g,
                          const float* __restrict__ be, __bf16* __restrict__ out) {
    const int row = blockIdx.x;
    const float4 xv = reinterpret_cast<const float4*>(x + (long)row * EMB)[threadIdx.x];
    float s = xv.x + xv.y + xv.z + xv.w;
    float sq = xv.x * xv.x + xv.y * xv.y + xv.z * xv.z + xv.w * xv.w;
    #pragma unroll
    for (int off = 32; off; off >>= 1) { s += __shfl_down(s, off); sq += __shfl_down(sq, off); }
    __shared__ float red[8];
    const int w = threadIdx.x >> 6, lane = threadIdx.x & 63;
    if (lane == 0) { red[w] = s; red[4 + w] = sq; }
    __syncthreads();
    if (threadIdx.x == 0) {
        float st = red[0] + red[1] + red[2] + red[3];
        float sqt = red[4] + red[5] + red[6] + red[7];
        float mean = st * (1.0f / EMB);
        float var = sqt * (1.0f / EMB) - mean * mean;
        red[0] = mean; red[1] = rsqrtf(var + 1e-5f);
    }
    __syncthreads();
    const float mean = red[0], rstd = red[1];
    const float4 gv = reinterpret_cast<const float4*>(g)[threadIdx.x];
    const float4 bv = reinterpret_cast<const float4*>(be)[threadIdx.x];
    bf16x4 o;
    o[0] = (__bf16)((xv.x - mean) * rstd * gv.x + bv.x);
    o[1] = (__bf16)((xv.y - mean) * rstd * gv.y + bv.y);
    o[2] = (__bf16)((xv.z - mean) * rstd * gv.z + bv.z);
    o[3] = (__bf16)((xv.w - mean) * rstd * gv.w + bv.w);
    *reinterpret_cast<bf16x4*>(out + (long)row * EMB + threadIdx.x * 4) = o;
}

// ---------------- bf16 GEMM (NT): C[M][N] = A[M][K] * BT[N][K]^T ----------------
template <int OUT_BF16, int RELU, int HAS_BIAS, int HAS_RES>
__global__ __launch_bounds__(256)
void gemm_nt(const __bf16* __restrict__ A, const __bf16* __restrict__ BT,
             const float* __restrict__ bias, const float* __restrict__ res,
             void* __restrict__ outp, int M, int N, int K) {
    __shared__ __bf16 As[128][72];
    __shared__ __bf16 Bs[128][72];
    const int t = threadIdx.x;
    const int w = t >> 6, lane = t & 63;
    const int wm = (w >> 1) * 64, wn = (w & 1) * 64;
    const int m0 = blockIdx.y * 128, n0 = blockIdx.x * 128;
    const int rA = lane & 15, kA = (lane >> 4) * 8;
    const int srow = t >> 3, sseg = t & 7;

    f32x4 acc[4][4] = {};
    for (int k0 = 0; k0 < K; k0 += 64) {
        bf16x8 ar[4], br[4];
        #pragma unroll
        for (int i = 0; i < 4; i++) {
            const int row = srow + 32 * i;
            ar[i] = *reinterpret_cast<const bf16x8*>(A + (long)(m0 + row) * K + k0 + sseg * 8);
            br[i] = *reinterpret_cast<const bf16x8*>(BT + (long)(n0 + row) * K + k0 + sseg * 8);
        }
        __syncthreads();
        #pragma unroll
        for (int i = 0; i < 4; i++) {
            const int row = srow + 32 * i;
            *reinterpret_cast<bf16x8*>(&As[row][sseg * 8]) = ar[i];
            *reinterpret_cast<bf16x8*>(&Bs[row][sseg * 8]) = br[i];
        }
        __syncthreads();
        #pragma unroll
        for (int kk = 0; kk < 2; kk++) {
            bf16x8 af[4], bfr[4];
            #pragma unroll
            for (int m = 0; m < 4; m++)
                af[m] = *reinterpret_cast<const bf16x8*>(&As[wm + m * 16 + rA][kk * 32 + kA]);
            #pragma unroll
            for (int n = 0; n < 4; n++)
                bfr[n] = *reinterpret_cast<const bf16x8*>(&Bs[wn + n * 16 + rA][kk * 32 + kA]);
            #pragma unroll
            for (int m = 0; m < 4; m++)
                #pragma unroll
                for (int n = 0; n < 4; n++)
                    acc[m][n] = __builtin_amdgcn_mfma_f32_16x16x32_bf16(af[m], bfr[n], acc[m][n], 0, 0, 0);
        }
    }
    const int rl = (lane >> 4) * 4, cl = lane & 15;
    #pragma unroll
    for (int m = 0; m < 4; m++) {
        #pragma unroll
        for (int n = 0; n < 4; n++) {
            const int gc = n0 + wn + n * 16 + cl;
            float bval = 0.0f;
            if (HAS_BIAS) bval = bias[gc];
            #pragma unroll
            for (int r = 0; r < 4; r++) {
                const int gr = m0 + wm + m * 16 + rl + r;
                float v = acc[m][n][r] + bval;
                if (HAS_RES) v += res[(long)gr * N + gc];
                if (RELU) v = fmaxf(v, 0.0f);
                if (OUT_BF16) ((__bf16*)outp)[(long)gr * N + gc] = (__bf16)v;
                else          ((float*)outp)[(long)gr * N + gc] = v;
            }
        }
    }
}

// ---------------- causal flash attention: LDS-staged, double-buffered ----------------
// K LDS tile: logical [64 kv][128B d], phys byte = row*128 + (col ^ ((row&7)<<4))
// V LDS tile: logical [64 d][128B kv], same swizzle.
template <int MASKED>
__device__ __forceinline__ void attn_compute(
    const char* __restrict__ Kl, const char* __restrict__ Vl,
    __bf16 (*__restrict__ PsW)[72],
    const bf16x8 (&qf)[2][2], const bf16x8& ones,
    f32x4 (&o)[2][4], f32x4 (&l5)[2], float (&mr)[2][4],
    int kv0, int rA, int g, int rl, int qw)
{
    const int swz = (rA & 7) << 4;
    bf16x8 kf[4][2];
    #pragma unroll
    for (int c = 0; c < 4; c++)
        #pragma unroll
        for (int kc = 0; kc < 2; kc++)
            kf[c][kc] = *reinterpret_cast<const bf16x8*>(
                Kl + (c * 16 + rA) * 128 + ((kc * 64 + g * 16) ^ swz));
    f32x4 sa[2][4];
    #pragma unroll
    for (int rt = 0; rt < 2; rt++)
        #pragma unroll
        for (int c = 0; c < 4; c++) {
            f32x4 acc = {};
            acc = __builtin_amdgcn_mfma_f32_16x16x32_bf16(qf[rt][0], kf[c][0], acc, 0, 0, 0);
            acc = __builtin_amdgcn_mfma_f32_16x16x32_bf16(qf[rt][1], kf[c][1], acc, 0, 0, 0);
            sa[rt][c] = acc;
        }
    #pragma unroll
    for (int rt = 0; rt < 2; rt++) {
        #pragma unroll
        for (int r = 0; r < 4; r++) {
            float s0 = sa[rt][0][r], s1 = sa[rt][1][r], s2 = sa[rt][2][r], s3 = sa[rt][3][r];
            if (MASKED) {
                const int gr = qw + rt * 16 + rl + r;
                if (kv0 + rA > gr)      s0 = -__builtin_inff();
                if (kv0 + 16 + rA > gr) s1 = -__builtin_inff();
                if (kv0 + 32 + rA > gr) s2 = -__builtin_inff();
                if (kv0 + 48 + rA > gr) s3 = -__builtin_inff();
            }
            float tm = fmaxf(fmaxf(s0, s1), fmaxf(s2, s3));
            #pragma unroll
            for (int msk = 1; msk < 16; msk <<= 1) tm = fmaxf(tm, __shfl_xor(tm, msk));
            const float mo = mr[rt][r];
            const float mn = fmaxf(mo, tm);
            mr[rt][r] = mn;
            const float sc = __expf(mo - mn);
            const float p0 = __expf(s0 - mn);
            const float p1 = __expf(s1 - mn);
            const float p2 = __expf(s2 - mn);
            const float p3 = __expf(s3 - mn);
            #pragma unroll
            for (int n = 0; n < 4; n++) o[rt][n][r] *= sc;
            l5[rt][r] *= sc;
            const int prow = rt * 16 + rl + r;
            PsW[prow][rA]      = (__bf16)p0;
            PsW[prow][16 + rA] = (__bf16)p1;
            PsW[prow][32 + rA] = (__bf16)p2;
            PsW[prow][48 + rA] = (__bf16)p3;
        }
    }
    // same-wave LDS write->read: drain DS queue
    asm volatile("s_waitcnt lgkmcnt(0)" ::: "memory");

    bf16x8 ap[2][2];
    #pragma unroll
    for (int rt = 0; rt < 2; rt++)
        #pragma unroll
        for (int ks = 0; ks < 2; ks++)
            ap[rt][ks] = *reinterpret_cast<const bf16x8*>(&PsW[rt * 16 + rA][ks * 32 + g * 8]);
    #pragma unroll
    for (int ks = 0; ks < 2; ks++) {
        #pragma unroll
        for (int rt = 0; rt < 2; rt++)
            l5[rt] = __builtin_amdgcn_mfma_f32_16x16x32_bf16(ap[rt][ks], ones, l5[rt], 0, 0, 0);
        #pragma unroll
        for (int n = 0; n < 4; n++) {
            bf16x8 bv = *reinterpret_cast<const bf16x8*>(
                Vl + (n * 16 + rA) * 128 + ((ks * 64 + g * 16) ^ swz));
            #pragma unroll
            for (int rt = 0; rt < 2; rt++)
                o[rt][n] = __builtin_amdgcn_mfma_f32_16x16x32_bf16(ap[rt][ks], bv, o[rt][n], 0, 0, 0);
        }
    }
}

// qkv: [B*T][3072] bf16 (Q pre-scaled by 1/32); Vt: [B*H][64][2048] bf16
// grid (T/128, B*H), 256 thr (4 waves x 32 Q-rows).
__global__ __launch_bounds__(256)
void attn_kernel(const __bf16* __restrict__ qkv, const __bf16* __restrict__ Vt,
                 __bf16* __restrict__ attn) {
    __shared__ __bf16 Ks[2][64 * 64];   // 8KB per buffer
    __shared__ __bf16 Vs[2][64 * 64];
    __shared__ __bf16 Ps[4][32][72];

    const int bh = blockIdx.y, b = bh >> 4, h = bh & 15;
    const int qtile = (int)gridDim.x - 1 - (int)blockIdx.x;  // heavy tiles dispatch first
    const int q0 = qtile * 128;
    const int w = threadIdx.x >> 6, lane = threadIdx.x & 63;
    const int qw = q0 + w * 32;
    const int rA = lane & 15, g = lane >> 4, rl = g * 4;
    const int srow8 = lane >> 3;
    const int scol = (lane & 7) * 16;          // byte col within 128B logical row
    const int wcol = scol ^ (srow8 << 4);      // swizzled LDS byte col

    const char* qb = (const char*)(qkv + (long)b * T_SEQ * 3072 + h * 64);
    const char* kb = qb + 2048;                       // K base (+1024 elems)
    const char* vtb = (const char*)(Vt + (long)bh * 64 * T_SEQ);

    bf16x8 qf[2][2];
    #pragma unroll
    for (int rt = 0; rt < 2; rt++)
        #pragma unroll
        for (int kc = 0; kc < 2; kc++)
            qf[rt][kc] = *reinterpret_cast<const bf16x8*>(
                qb + (long)(qw + rt * 16 + rA) * 6144 + kc * 64 + g * 16);

    bf16x8 ones;
    #pragma unroll
    for (int i = 0; i < 8; i++) ones[i] = (__bf16)1.0f;

    f32x4 o[2][4] = {};
    f32x4 l5[2] = {};
    float mr[2][4];
    #pragma unroll
    for (int rt = 0; rt < 2; rt++)
        #pragma unroll
        for (int r = 0; r < 4; r++) mr[rt][r] = -__builtin_inff();

    const int nsteps = q0 / 64 + 2;
    const int t_avail = qw + 32;
    const int isK = (w < 2);
    const int r0 = (w & 1) * 32 + srow8;       // staging row base for this lane

    bf16x8 stg[4];
    auto issue = [&](int kv0) {
        if (isK) {
            #pragma unroll
            for (int i = 0; i < 4; i++)
                stg[i] = *reinterpret_cast<const bf16x8*>(kb + (long)(kv0 + r0 + i * 8) * 6144 + scol);
        } else {
            #pragma unroll
            for (int i = 0; i < 4; i++)
                stg[i] = *reinterpret_cast<const bf16x8*>(vtb + (long)(r0 + i * 8) * 4096 + kv0 * 2 + scol);
        }
    };
    auto lwrite = [&](int buf) {
        char* base = isK ? (char*)Ks[buf] : (char*)Vs[buf];
        #pragma unroll
        for (int i = 0; i < 4; i++)
            *reinterpret_cast<bf16x8*>(base + (r0 + i * 8) * 128 + wcol) = stg[i];
    };

    issue(0);
    lwrite(0);
    __syncthreads();

    for (int t = 0; t < nsteps; ++t) {
        const int kv0 = t * 64, cur = t & 1;
        const bool has_next = (t + 1 < nsteps);
        if (has_next) issue(kv0 + 64);         // async: hides under compute
        if (kv0 < t_avail) {
            if (kv0 + 64 <= qw)
                attn_compute<0>((const char*)Ks[cur], (const char*)Vs[cur], Ps[w],
                                qf, ones, o, l5, mr, kv0, rA, g, rl, qw);
            else
                attn_compute<1>((const char*)Ks[cur], (const char*)Vs[cur], Ps[w],
                                qf, ones, o, l5, mr, kv0, rA, g, rl, qw);
        }
        if (has_next) lwrite(cur ^ 1);         // write next buffer (safe: barrier-separated)
        __syncthreads();
    }

    #pragma unroll
    for (int rt = 0; rt < 2; rt++)
        #pragma unroll
        for (int n = 0; n < 4; n++)
            #pragma unroll
            for (int r = 0; r < 4; r++) {
                const int gr = qw + rt * 16 + rl + r;
                attn[(long)(b * T_SEQ + gr) * EMB + h * 64 + n * 16 + rA] =
                    (__bf16)(o[rt][n][r] / l5[rt][r]);
            }
}

// ---------------- launch ----------------
extern "C" void kernel_launch(void* const* d_in, const int* in_sizes, int n_in,
                              void* d_out, int out_size, void* d_ws, size_t ws_size,
                              hipStream_t stream) {
    const float* x      = (const float*)d_in[0];
    const float* wq     = (const float*)d_in[1];
    const float* wk     = (const float*)d_in[2];
    const float* wv     = (const float*)d_in[3];
    const float* w_proj = (const float*)d_in[4];
    const float* b_proj = (const float*)d_in[5];
    const float* w1     = (const float*)d_in[6];
    const float* b1     = (const float*)d_in[7];
    const float* w2     = (const float*)d_in[8];
    const float* b2     = (const float*)d_in[9];
    const float* g1     = (const float*)d_in[10];
    const float* be1    = (const float*)d_in[11];
    const float* g2     = (const float*)d_in[12];
    const float* be2    = (const float*)d_in[13];
    float* out = (float*)d_out;

    char* ws = (char*)d_ws;
    __bf16* WqkvT = (__bf16*)ws;  ws += 3072L * 1024 * 2;
    __bf16* WprojT = (__bf16*)ws; ws += 1024L * 1024 * 2;
    __bf16* W1T = (__bf16*)ws;    ws += 4096L * 1024 * 2;
    __bf16* W2T = (__bf16*)ws;    ws += 1024L * 4096 * 2;
    __bf16* h1  = (__bf16*)ws;    ws += 4096L * 1024 * 2;
    __bf16* qkvb = (__bf16*)ws;
    __bf16* attnb = (__bf16*)(ws + 4096L * 3072 * 2);
    __bf16* ffb = (__bf16*)ws;    ws += 4096L * 3072 * 2 + 4096L * 1024 * 2;
    float* x2 = (float*)ws;
    __bf16* Vt = (__bf16*)ws;   // overlays x2 (dead before proj-GEMM writes x2)

    const dim3 tb(32, 8);
    transpose_cvt<<<dim3(2, 32, 16), tb, 0, stream>>>(wq, WqkvT,                1024, 64, 65536L, 65536L, 0.03125f);
    transpose_cvt<<<dim3(2, 32, 16), tb, 0, stream>>>(wk, WqkvT + 1024L * 1024, 1024, 64, 65536L, 65536L, 1.0f);
    transpose_cvt<<<dim3(2, 32, 16), tb, 0, stream>>>(wv, WqkvT + 2048L * 1024, 1024, 64, 65536L, 65536L, 1.0f);
    transpose_cvt<<<dim3(32, 32, 1),  tb, 0, stream>>>(w_proj, WprojT, 1024, 1024, 0, 0, 1.0f);
    transpose_cvt<<<dim3(128, 32, 1), tb, 0, stream>>>(w1, W1T, 1024, 4096, 0, 0, 1.0f);
    transpose_cvt<<<dim3(32, 128, 1), tb, 0, stream>>>(w2, W2T, 4096, 1024, 0, 0, 1.0f);

    ln_kernel<<<4096, 256, 0, stream>>>(x, g1, be1, h1);
    gemm_nt<1, 0, 0, 0><<<dim3(24, 32), 256, 0, stream>>>(h1, WqkvT, nullptr, nullptr, qkvb, 4096, 3072, 1024);
    vt_transpose<<<dim3(32, 32), 256, 0, stream>>>(qkvb, Vt);
    attn_kernel<<<dim3(16, 32), 256, 0, stream>>>(qkvb, Vt, attnb);
    gemm_nt<0, 0, 1, 1><<<dim3(8, 32), 256, 0, stream>>>(attnb, WprojT, b_proj, x, x2, 4096, 1024, 1024);
    ln_kernel<<<4096, 256, 0, stream>>>(x2, g2, be2, h1);
    gemm_nt<1, 1, 1, 0><<<dim3(32, 32), 256, 0, stream>>>(h1, W1T, b1, nullptr, ffb, 4096, 4096, 1024);
    gemm_nt<0, 0, 1, 1><<<dim3(8, 32), 256, 0, stream>>>(ffb, W2T, b2, x2, out, 4096, 1024, 4096);
}